// Round 2
// baseline (2437.603 us; speedup 1.0000x reference)
//
#include <hip/hip_runtime.h>
#include <hip/hip_bf16.h>

typedef __bf16 bf16x8 __attribute__((ext_vector_type(8)));
typedef float  f32x4  __attribute__((ext_vector_type(4)));

#define M_TOT  8192
#define N_TOT  4096
#define K_TOT  4096
#define NCH    32      // k-chunks (128 k each)
#define CCOLS  512     // n-columns per workgroup (32 n-blocks)
#define NBL_WG 32
#define NBL_W  8       // n-blocks per wave
#define BM     16      // m-rows per workgroup

// Mask storage-width flags, detected on-device each call.
__device__ int g_flags;

// ---------------------------------------------------------------------------
// Detect mask storage width: 1 B (bool/int8), 2 B (bf16/fp16), 4 B (int32/fp32).
// (verbatim from previous passing kernel)
// ---------------------------------------------------------------------------
__global__ void bsl_detect(const unsigned char* __restrict__ mask) {
    __shared__ int sf[256];
    const int t = threadIdx.x;
    int f = 0;
    for (int i = t * 256; i < t * 256 + 256; ++i) {
        unsigned char b = mask[i];
        if (b) {
            if ((i & 1) && b == 1) f |= 1;
            if ((i & 3) == 1 && (b == 0x3F || b == 0x80 || b == 0x3C)) f |= 2;
        }
    }
    sf[t] = f;
    __syncthreads();
    if (t == 0) {
        int acc = 0;
        for (int i = 0; i < 256; ++i) acc |= sf[i];
        g_flags = acc;
    }
}

// ---------------------------------------------------------------------------
// Block-sparse GEMM. Workgroup = 16 m-rows x 512 n-cols; wave owns 8 n-blocks
// (acc = 8 x f32x4 = 32 regs -> 4+ waves/SIMD with launch_bounds(256,4)).
// Grid (8, 512): wgid%8 == n-chunk -> each XCD serves one n-chunk; its active
// W (~0.86 MB) stays L2-resident, x re-reads come from L3 (134 MB fits).
// Per 128-k chunk: x staged fp32->bf16 to double-buffered LDS (ONE barrier per
// chunk; next-chunk prefetch issued AFTER the barrier so the barrier's vmcnt
// drain never exposes fresh loads). Inner loop: per owned n-block, the 8-bit
// active mask is decoded BRANCHLESSLY into 4 static pair-slots (ctz chain);
// invalid slots alias a valid address and multiply W by 0; half-active pairs
// zero the dead half. All loads of a group are control-flow-free -> compiler
// batches them (one latency depth per n-block group, not per MFMA).
// ---------------------------------------------------------------------------
__global__ __launch_bounds__(256, 4) void bsl_gemm(
        const float* __restrict__ x,
        const float* __restrict__ w,
        const float* __restrict__ bias,
        const unsigned char* __restrict__ mask,
        float* __restrict__ out) {
    __shared__ __hip_bfloat16 xs[2][BM][136];   // stride 136: 2-way banks (free), 16B-aligned rows
    __shared__ unsigned char  nbm[NCH][NBL_WG]; // [chunk][n-block] active-kb bits

    const int nc   = blockIdx.x;          // n-chunk 0..7 == XCD
    const int m0   = blockIdx.y * BM;
    const int t    = threadIdx.x;
    const int wq   = t >> 6;
    const int lane = t & 63;
    const int q    = lane >> 4;
    const int rl   = lane & 15;

    // --- chunk-0 x prefetch (latency hides under mask scan) ---
    const int srow = t >> 4;              // 0..15
    const int sseg = t & 15;              // 0..15 (8 floats each)
    const float* xrow = x + (size_t)(m0 + srow) * K_TOT + sseg * 8;
    float4 p0 = ((const float4*)xrow)[0];
    float4 p1 = ((const float4*)xrow)[1];

    // --- build per-(chunk, n-block) activity bytes from block head elements ---
    {
        const int flags = g_flags;
        const int nb  = t >> 3;            // 0..31
        const int chb = (t & 7) * 4;       // 4 chunks per thread
        const size_t rowe = (size_t)(nc * CCOLS + nb * 16) * K_TOT;
        #pragma unroll
        for (int p = 0; p < 4; ++p) {
            const int ch = chb + p;
            unsigned int bb = 0;
            #pragma unroll
            for (int i = 0; i < 8; ++i) {
                const size_t e = rowe + (size_t)(ch * 8 + i) * 16;
                unsigned int v;
                if (flags & 1)      v = mask[e];
                else if (flags & 2) v = ((const unsigned short*)mask)[e];
                else                v = ((const unsigned int*)mask)[e];
                bb |= (unsigned int)(v != 0u) << i;
            }
            nbm[ch][nb] = (unsigned char)bb;
        }
    }

    f32x4 acc[NBL_W];
    #pragma unroll
    for (int i = 0; i < NBL_W; ++i) acc[i] = (f32x4){0.f, 0.f, 0.f, 0.f};

    // W base: row (nc*512 + wq*128 + rl)
    const float* wbase = w + (size_t)(nc * CCOLS + wq * (NBL_W * 16) + rl) * K_TOT;

    __syncthreads();   // nbm ready

    int buf = 0;
    for (int ch = 0; ch < NCH; ++ch) {
        // ---- stage current chunk from regs (loaded a full chunk ago) ----
        {
            union { __hip_bfloat16 h[8]; uint4 u; } cv;
            const float ff[8] = {p0.x, p0.y, p0.z, p0.w, p1.x, p1.y, p1.z, p1.w};
            #pragma unroll
            for (int e = 0; e < 8; ++e) cv.h[e] = __float2bfloat16(ff[e]);
            *(uint4*)&xs[buf][srow][sseg * 8] = cv.u;
        }
        __syncthreads();   // single barrier per chunk (double-buffered xs)

        // ---- issue next-chunk prefetch AFTER the barrier ----
        if (ch + 1 < NCH) {
            const float* nx = xrow + (ch + 1) * 128;
            p0 = ((const float4*)nx)[0];
            p1 = ((const float4*)nx)[1];
        }

        // wave's 8 activity bytes: one uniform 8-B LDS read
        const unsigned long long bw = *(const unsigned long long*)&nbm[ch][wq * NBL_W];

        #pragma unroll
        for (int nbl = 0; nbl < NBL_W; ++nbl) {
            const unsigned int b = (unsigned int)(bw >> (8 * nbl)) & 0xffu;
            if (!b) continue;                       // wave-uniform skip
            const unsigned int pm = (b | (b >> 1)) & 0x55u;  // active pairs (even bits)
            const int cnt = __popc(pm);
            unsigned int pr = pm;
            const float* wp = wbase + (size_t)nbl * (16 * K_TOT) + ch * 128;
            #pragma unroll
            for (int s = 0; s < 4; ++s) {
                const bool valid = (s < cnt);
                const int bitpos = __builtin_ctz(pr | 0x100u);   // 8 when empty
                pr &= pr - 1u;
                const int pp  = valid ? (bitpos >> 1) : 0;
                const int kb0 = 2 * pp, kb1 = 2 * pp + 1;
                const int kb  = (q < 2) ? kb0 : kb1;
                const unsigned int mybit =
                    valid ? ((b >> kb) & 1u) : 0u;   // zero dead half / dead slot
                // W load (branchless; invalid slots alias pp=0, L1-hit)
                const float4* wv = (const float4*)(wp + kb * 16 + (q & 1) * 8);
                float4 f0 = wv[0], f1 = wv[1];
                // A fragment from LDS
                bf16x8 a = *(const bf16x8*)&xs[buf][rl][kb * 16 + (q & 1) * 8];
                // convert W with zero-select
                const float zm = (float)mybit;
                union { __hip_bfloat16 h[8]; bf16x8 v; } cb;
                const float gg[8] = {f0.x, f0.y, f0.z, f0.w, f1.x, f1.y, f1.z, f1.w};
                #pragma unroll
                for (int e = 0; e < 8; ++e) cb.h[e] = __float2bfloat16(gg[e] * zm);
                acc[nbl] = __builtin_amdgcn_mfma_f32_16x16x32_bf16(a, cb.v, acc[nbl], 0, 0, 0);
            }
        }
        buf ^= 1;
    }

    // ---- epilogue: C/D layout col=lane&15, row=q*4+reg ----
    #pragma unroll
    for (int nbl = 0; nbl < NBL_W; ++nbl) {
        const int col = nc * CCOLS + (wq * NBL_W + nbl) * 16 + rl;
        const float bv = bias[col];
        #pragma unroll
        for (int rg = 0; rg < 4; ++rg) {
            out[(size_t)(m0 + q * 4 + rg) * N_TOT + col] = acc[nbl][rg] + bv;
        }
    }
}

extern "C" void kernel_launch(void* const* d_in, const int* in_sizes, int n_in,
                              void* d_out, int out_size, void* d_ws, size_t ws_size,
                              hipStream_t stream) {
    const float* x    = (const float*)d_in[0];
    const float* w    = (const float*)d_in[1];
    const float* bias = (const float*)d_in[2];
    const unsigned char* mask = (const unsigned char*)d_in[3];
    float* out = (float*)d_out;

    bsl_detect<<<1, 256, 0, stream>>>(mask);

    dim3 grid(N_TOT / CCOLS, M_TOT / BM);   // (8, 512): wgid%8 == nc == XCD
    bsl_gemm<<<grid, 256, 0, stream>>>(x, w, bias, mask, out);
}

// Round 3
// 492.456 us; speedup vs baseline: 4.9499x; 4.9499x over previous
//
#include <hip/hip_runtime.h>
#include <hip/hip_bf16.h>

typedef __bf16 bf16x8 __attribute__((ext_vector_type(8)));
typedef float  f32x4  __attribute__((ext_vector_type(4)));

#define M_TOT 8192
#define N_TOT 4096
#define K_TOT 4096
#define NCH   32          // 128-k chunks
#define NBROW 256         // 16-wide n-block rows
#define CAP   160         // max compacted tiles per n-block row (incl. pads)

// ws layout (bytes)
#define XP_BYTES   ((size_t)M_TOT * K_TOT * 2)            // 67,108,864
#define WT_BYTES   ((size_t)NBROW * CAP * 512)            // 20,971,520
#define META_BYTES ((size_t)NBROW * CAP)                  // 40,960
#define SEG_BYTES  ((size_t)NBROW * NCH * 4)              // 32,768
#define WS_NEED    (XP_BYTES + WT_BYTES + META_BYTES + SEG_BYTES)

__device__ int g_flags;

__device__ __forceinline__ void gload_lds16(const void* g, void* l) {
    __builtin_amdgcn_global_load_lds(
        (const __attribute__((address_space(1))) unsigned int*)g,
        (__attribute__((address_space(3))) unsigned int*)l, 16, 0, 0);
}

// ---------------------------------------------------------------------------
// Detect mask storage width (verbatim from passing kernel).
// ---------------------------------------------------------------------------
__global__ void bsl_detect(const unsigned char* __restrict__ mask) {
    __shared__ int sf[256];
    const int t = threadIdx.x;
    int f = 0;
    for (int i = t * 256; i < t * 256 + 256; ++i) {
        unsigned char b = mask[i];
        if (b) {
            if ((i & 1) && b == 1) f |= 1;
            if ((i & 3) == 1 && (b == 0x3F || b == 0x80 || b == 0x3C)) f |= 2;
        }
    }
    sf[t] = f;
    __syncthreads();
    if (t == 0) {
        int acc = 0;
        for (int i = 0; i < 256; ++i) acc |= sf[i];
        g_flags = acc;
    }
}

// ---------------------------------------------------------------------------
// prep_x: fp32 -> bf16, PRE-SWIZZLED: within each 128-k chunk, 16B-unit index
// u (0..15) is stored at u ^ (row & 7). GEMM stages with LINEAR global_load_lds
// and reads fragments with the same XOR -> conflict-optimal ds_read_b128.
// Writes stay inside their 128B line (XOR flips only low 3 bits) -> coalesced.
// ---------------------------------------------------------------------------
__global__ __launch_bounds__(256) void prep_x(
        const float* __restrict__ x, __hip_bfloat16* __restrict__ xp) {
    const long long tid    = (long long)blockIdx.x * 256 + threadIdx.x;
    const long long stride = (long long)gridDim.x * 256;
    const long long TOT    = (long long)M_TOT * K_TOT / 8;
    for (long long g = tid; g < TOT; g += stride) {
        const int row = (int)(g >> 9);        // 512 8-elem groups per row
        const int gi  = (int)(g & 511);
        const int ch  = gi >> 4;
        const int u   = gi & 15;
        const int up  = u ^ (row & 7);
        const float4 f0 = ((const float4*)(x + g * 8))[0];
        const float4 f1 = ((const float4*)(x + g * 8))[1];
        union { __hip_bfloat16 h[8]; uint4 v; } cv;
        const float ff[8] = {f0.x, f0.y, f0.z, f0.w, f1.x, f1.y, f1.z, f1.w};
        #pragma unroll
        for (int e = 0; e < 8; ++e) cv.h[e] = __float2bfloat16(ff[e]);
        *(uint4*)((char*)xp + (size_t)row * 8192 + ch * 256 + up * 16) = cv.v;
    }
}

// ---------------------------------------------------------------------------
// prep_w: one wg per n-block row j. Compact active 16x16 blocks into contiguous
// bf16 tiles ([n][k], 512B each), per-chunk segments PADDED TO EVEN with zero
// tiles. seg32[j][ch] = (tile_off<<16) | padded_len. meta = chunk-local kb.
// ---------------------------------------------------------------------------
__global__ __launch_bounds__(256) void prep_w(
        const float* __restrict__ w, const unsigned char* __restrict__ mask,
        __hip_bfloat16* __restrict__ wt, unsigned char* __restrict__ meta,
        unsigned int* __restrict__ seg32) {
    __shared__ int cnt[NCH];
    __shared__ unsigned short offl[NCH + 1];
    __shared__ short slotmap[CAP];

    const int j    = blockIdx.x;
    const int t    = threadIdx.x;     // == global k-block 0..255
    const int lane = t & 63;
    const int flags = g_flags;

    // head element of block (j, t)
    unsigned int v;
    {
        const size_t e = (size_t)(j * 16) * K_TOT + (size_t)t * 16;
        if (flags & 1)      v = mask[e];
        else if (flags & 2) v = ((const unsigned short*)mask)[e];
        else                v = ((const unsigned int*)mask)[e];
    }
    const bool act = (v != 0u);
    const unsigned long long bal = __ballot(act);
    const unsigned int cb = (unsigned int)((bal >> ((lane >> 3) * 8)) & 0xffu);
    if ((lane & 7) == 0) cnt[t >> 3] = __popc(cb);
    if (t < CAP) slotmap[t] = -1;
    __syncthreads();

    if (t == 0) {
        int o = 0;
        for (int ch = 0; ch < NCH; ++ch) {
            int pl = cnt[ch] + (cnt[ch] & 1);        // pad to even
            const int avail = CAP - o;
            if (pl > avail) pl = avail & ~1;         // astronomically unlikely
            offl[ch] = (unsigned short)o;
            seg32[j * NCH + ch] = ((unsigned int)o << 16) | (unsigned int)pl;
            o += pl;
        }
        offl[NCH] = (unsigned short)o;
    }
    __syncthreads();

    if (act) {
        const int ch   = t >> 3;
        const int rank = __popc(cb & ((1u << (lane & 7)) - 1u));
        const int slot = offl[ch] + rank;
        if (slot < (int)offl[ch + 1]) slotmap[slot] = (short)t;
    }
    __syncthreads();

    const int total = offl[NCH];
    for (int s = 0; s < total; ++s) {
        const int kbg = slotmap[s];
        float val = 0.f;
        if (kbg >= 0)
            val = w[(size_t)(j * 16 + (t >> 4)) * K_TOT + (unsigned)kbg * 16 + (t & 15)];
        wt[(size_t)(j * CAP + s) * 256 + t] = __float2bfloat16(val);
    }
    if (t < total) {
        const int kbg = slotmap[t];
        meta[j * CAP + t] = (kbg < 0) ? 0 : (unsigned char)(kbg & 7);
    }
}

// ---------------------------------------------------------------------------
// Main GEMM from preprocessed data. wg = 64 m x 256 n; 4 waves x 4 n-blocks;
// acc[4][4] f32x4 (static indices). Per chunk: 4 global_load_lds dwordx4 per
// wave (double-buffered; prefetch issued BEFORE compute so the barrier drain
// hides under it), then per n-block only the REAL active pairs:
//   1 coalesced 1KB W-tile-pair load + 1 u16 meta + 4 swizzled ds_read_b128
//   + 4 mfma_16x16x32_bf16.
// Grid (16, 128): wgid%8 = jg%8 -> n-group pinned per XCD (W slice ~0.4 MB L2).
// ---------------------------------------------------------------------------
__global__ __launch_bounds__(256, 4) void bsl_gemm_ws(
        const __hip_bfloat16* __restrict__ xp,
        const __hip_bfloat16* __restrict__ wt,
        const unsigned char*  __restrict__ meta,
        const unsigned int*   __restrict__ seg32,
        const float* __restrict__ bias,
        float* __restrict__ out) {
    __shared__ __align__(16) __hip_bfloat16 xs[2][64][128];   // 2 x 16 KB

    const int jg   = blockIdx.x;          // n-group (256 cols)
    const int m0   = blockIdx.y * 64;
    const int t    = threadIdx.x;
    const int wq   = t >> 6;
    const int lane = t & 63;
    const int q    = lane >> 4;
    const int rl   = lane & 15;
    const int r7   = rl & 7;

    // staging source: wave wq stages rows wq*16 .. wq*16+15 (4 issues x 4 rows)
    const char* xsrc = (const char*)xp
        + (size_t)(m0 + wq * 16 + q) * 8192 + rl * 16;
    char* const xsb = (char*)&xs[0][0][0];

    const int laneoff_w = (q >> 1) * 512 + rl * 32 + (q & 1) * 16;

    f32x4 acc[4][4];
    #pragma unroll
    for (int i = 0; i < 4; ++i)
        #pragma unroll
        for (int s = 0; s < 4; ++s) acc[i][s] = (f32x4){0.f, 0.f, 0.f, 0.f};

    auto stage = [&](int b, int ch) {
        const char* s0 = xsrc + (size_t)ch * 256;
        char* d0 = xsb + b * 16384 + wq * 4096;
        #pragma unroll
        for (int i = 0; i < 4; ++i)
            gload_lds16(s0 + (size_t)i * (4 * 8192), d0 + i * 1024);
    };

    stage(0, 0);
    __syncthreads();

    int buf = 0;
    for (int ch = 0; ch < NCH; ++ch) {
        if (ch + 1 < NCH) stage(buf ^ 1, ch + 1);

        const char* xcur = xsb + buf * 16384;
        #pragma unroll
        for (int i = 0; i < 4; ++i) {
            const int j  = jg * 16 + wq * 4 + i;
            const unsigned int sg = seg32[j * NCH + ch];
            const int np = (int)(sg & 0xffffu) >> 1;
            const char* wbase = (const char*)wt + (size_t)(j * CAP + (sg >> 16)) * 512;
            const unsigned char* mbase = meta + j * CAP + (sg >> 16);
            for (int p = 0; p < np; ++p) {
                const unsigned short mm = *(const unsigned short*)(mbase + 2 * p);
                const int kb_a = mm & 7;
                const int kb_b = (mm >> 8) & 7;
                bf16x8 b = *(const bf16x8*)(wbase + (size_t)p * 1024 + laneoff_w);
                const int kbs = (q < 2) ? kb_a : kb_b;
                const int swz = ((kbs * 2 + (q & 1)) ^ r7) * 16;
                #pragma unroll
                for (int s = 0; s < 4; ++s) {
                    bf16x8 a = *(const bf16x8*)(xcur + s * 4096 + rl * 256 + swz);
                    acc[i][s] = __builtin_amdgcn_mfma_f32_16x16x32_bf16(a, b, acc[i][s], 0, 0, 0);
                }
            }
        }
        __syncthreads();
        buf ^= 1;
    }

    // epilogue: C/D layout col=lane&15, row=q*4+reg
    #pragma unroll
    for (int i = 0; i < 4; ++i) {
        const int j   = jg * 16 + wq * 4 + i;
        const int col = j * 16 + rl;
        const float bv = bias[col];
        #pragma unroll
        for (int s = 0; s < 4; ++s)
            #pragma unroll
            for (int rg = 0; rg < 4; ++rg)
                out[(size_t)(m0 + s * 16 + q * 4 + rg) * N_TOT + col] = acc[i][s][rg] + bv;
    }
}

// ---------------------------------------------------------------------------
// Fallback (ws too small): verbatim round-0 kernel, measured 730 us.
// ---------------------------------------------------------------------------
#define FBM 128
__global__ __launch_bounds__(256) void bsl_gemm_fb(
        const float* __restrict__ x,
        const float* __restrict__ w,
        const float* __restrict__ bias,
        const unsigned char* __restrict__ mask,
        float* __restrict__ out) {
    __shared__ __hip_bfloat16 xs[FBM][40];
    __shared__ __hip_bfloat16 wls[16][40];
    __shared__ unsigned long long sball[4];
    __shared__ unsigned char klist[256];

    const int j    = blockIdx.x;
    const int m0   = blockIdx.y * FBM;
    const int t    = threadIdx.x;
    const int wave = t >> 6;
    const int lane = t & 63;
    const int q    = lane >> 4;
    const int rl   = lane & 15;

    const int flags = g_flags;
    unsigned int v;
    {
        const long long e = (long long)(j * 16) * K_TOT + (long long)t * 16;
        if (flags & 1)      v = mask[e];
        else if (flags & 2) v = ((const unsigned short*)mask)[e];
        else                v = ((const unsigned int*)mask)[e];
    }
    const bool active = (v != 0);
    const unsigned long long bal = __ballot(active);
    if (lane == 0) sball[wave] = bal;
    __syncthreads();
    int count = 0;
    #pragma unroll
    for (int wv = 0; wv < 4; ++wv) count += __popcll(sball[wv]);
    if (active) {
        int pos = __popcll(bal & ((1ull << lane) - 1));
        for (int wv = 0; wv < wave; ++wv) pos += __popcll(sball[wv]);
        klist[pos] = (unsigned char)t;
    }
    __syncthreads();

    const int r  = t >> 1;
    const int hh = t & 1;

    f32x4 acc0 = {0.f, 0.f, 0.f, 0.f};
    f32x4 acc1 = {0.f, 0.f, 0.f, 0.f};

    const int npairs = (count + 1) >> 1;
    for (int p = 0; p < npairs; ++p) {
        const int  kb1  = klist[2 * p];
        const bool has2 = (2 * p + 1) < count;
        const int  kb2  = has2 ? (int)klist[2 * p + 1] : kb1;
        const int  kb   = hh ? kb2 : kb1;
        {
            const float4* src = (const float4*)(x + (long long)(m0 + r) * K_TOT + kb * 16);
            float4 f0 = src[0], f1 = src[1], f2 = src[2], f3 = src[3];
            union { __hip_bfloat16 h[16]; uint4 u[2]; } cv;
            const float ff[16] = {f0.x, f0.y, f0.z, f0.w, f1.x, f1.y, f1.z, f1.w,
                                  f2.x, f2.y, f2.z, f2.w, f3.x, f3.y, f3.z, f3.w};
            #pragma unroll
            for (int e = 0; e < 16; ++e) cv.h[e] = __float2bfloat16(ff[e]);
            *(uint4*)(&xs[r][hh * 16])     = cv.u[0];
            *(uint4*)(&xs[r][hh * 16 + 8]) = cv.u[1];
        }
        if (t < 32) {
            const int rw = t >> 1;
            const bool valid = (hh == 0) || has2;
            float4 f0 = {0,0,0,0}, f1 = {0,0,0,0}, f2 = {0,0,0,0}, f3 = {0,0,0,0};
            if (valid) {
                const float4* wsrc = (const float4*)(w + (long long)(j * 16 + rw) * K_TOT + kb * 16);
                f0 = wsrc[0]; f1 = wsrc[1]; f2 = wsrc[2]; f3 = wsrc[3];
            }
            union { __hip_bfloat16 h[16]; uint4 u[2]; } cv;
            const float ff[16] = {f0.x, f0.y, f0.z, f0.w, f1.x, f1.y, f1.z, f1.w,
                                  f2.x, f2.y, f2.z, f2.w, f3.x, f3.y, f3.z, f3.w};
            #pragma unroll
            for (int e = 0; e < 16; ++e) cv.h[e] = __float2bfloat16(ff[e]);
            *(uint4*)(&wls[rw][hh * 16])     = cv.u[0];
            *(uint4*)(&wls[rw][hh * 16 + 8]) = cv.u[1];
        }
        __syncthreads();

        bf16x8 bf = *(const bf16x8*)(&wls[rl][q * 8]);
        bf16x8 a0 = *(const bf16x8*)(&xs[wave * 32 + rl][q * 8]);
        bf16x8 a1 = *(const bf16x8*)(&xs[wave * 32 + 16 + rl][q * 8]);
        acc0 = __builtin_amdgcn_mfma_f32_16x16x32_bf16(a0, bf, acc0, 0, 0, 0);
        acc1 = __builtin_amdgcn_mfma_f32_16x16x32_bf16(a1, bf, acc1, 0, 0, 0);
        __syncthreads();
    }

    const float bv = bias[j * 16 + rl];
    #pragma unroll
    for (int i2 = 0; i2 < 2; ++i2) {
        f32x4 a = i2 ? acc1 : acc0;
        const int base_m = m0 + wave * 32 + i2 * 16 + q * 4;
        #pragma unroll
        for (int rg = 0; rg < 4; ++rg) {
            out[(long long)(base_m + rg) * N_TOT + j * 16 + rl] = a[rg] + bv;
        }
    }
}

extern "C" void kernel_launch(void* const* d_in, const int* in_sizes, int n_in,
                              void* d_out, int out_size, void* d_ws, size_t ws_size,
                              hipStream_t stream) {
    const float* x    = (const float*)d_in[0];
    const float* w    = (const float*)d_in[1];
    const float* bias = (const float*)d_in[2];
    const unsigned char* mask = (const unsigned char*)d_in[3];
    float* out = (float*)d_out;

    bsl_detect<<<1, 256, 0, stream>>>(mask);

    if (d_ws != nullptr && ws_size >= WS_NEED) {
        char* wsb = (char*)d_ws;
        __hip_bfloat16* xp   = (__hip_bfloat16*)wsb;
        __hip_bfloat16* wtl  = (__hip_bfloat16*)(wsb + XP_BYTES);
        unsigned char*  meta = (unsigned char*)(wsb + XP_BYTES + WT_BYTES);
        unsigned int*   seg  = (unsigned int*)(wsb + XP_BYTES + WT_BYTES + META_BYTES);

        prep_x<<<2048, 256, 0, stream>>>(x, xp);
        prep_w<<<NBROW, 256, 0, stream>>>(w, mask, wtl, meta, seg);
        dim3 grid(N_TOT / 256, M_TOT / 64);   // (16, 128)
        bsl_gemm_ws<<<grid, 256, 0, stream>>>(xp, wtl, meta, seg, bias, out);
    } else {
        dim3 grid(256, M_TOT / FBM);          // (256, 64)
        bsl_gemm_fb<<<grid, 256, 0, stream>>>(x, w, bias, mask, out);
    }
}